// Round 2
// baseline (628.933 us; speedup 1.0000x reference)
//
#include <hip/hip_runtime.h>
#include <math.h>

#define B_ 1024
#define D_ 1024
#define N_ 128
#define PT_ 28
#define KSEL 32            // softmax over top 32 (k=33, last dropped)
#define NOISE_EPS_ 0.01f

typedef float fx4 __attribute__((ext_vector_type(4)));   // native vec for nt-store

// ---------------- Kernel 1a: unique t_embed rows ue[28][1024] (fp32) ---------
// grid (28, 8) x 256 threads (4 waves). Block (s, y) computes 128 outputs
// ue[s][y*128 .. y*128+127] via wave-wide coalesced dot products.
__global__ __launch_bounds__(256) void embed_kernel(
    const float* __restrict__ w1, const float* __restrict__ b1,
    const float* __restrict__ w2, const float* __restrict__ b2,
    float* __restrict__ ue)
{
    __shared__ __align__(16) float h[D_];
    const int s = blockIdx.x;
    const int tid = threadIdx.x;
    const float sf = (float)s;
    for (int d = tid; d < D_; d += 256) {
        float x = sf * w1[d] + b1[d];          // t @ w1.T + b1  (w1 is [D,1])
        h[d] = x / (1.0f + expf(-x));          // SiLU
    }
    __syncthreads();
    const int wave = tid >> 6;
    const int lane = tid & 63;
    const fx4* __restrict__ h4 = (const fx4*)h;
    // each wave: 32 outputs, full-wave coalesced dot (1024B per load instr)
    for (int j = 0; j < 32; ++j) {
        const int i = blockIdx.y * 128 + wave * 32 + j;
        const fx4* __restrict__ row = (const fx4*)(w2 + (size_t)i * D_);
        float acc = 0.0f;
        #pragma unroll
        for (int k = 0; k < 4; ++k) {
            fx4 u  = row[k * 64 + lane];
            fx4 hv = h4 [k * 64 + lane];
            acc += u.x * hv.x + u.y * hv.y + u.z * hv.z + u.w * hv.w;
        }
        #pragma unroll
        for (int off = 32; off; off >>= 1) acc += __shfl_down(acc, off, 64);
        if (lane == 0) ue[(size_t)s * D_ + i] = acc + b2[i];
    }
}

// ------- Kernel 1b: unique clean logits + noise_std, uclean/unstd[28][128] ---
// grid 28 x 256 threads (4 waves). Coalesced gate_w row dots (wave-wide) and
// lane-owns-n accumulation for w_noise columns.
__global__ __launch_bounds__(256) void gate_precompute_kernel(
    const float* __restrict__ gate_w, const float* __restrict__ gate_b,
    const float* __restrict__ w_noise, const int* __restrict__ timestep,
    const float* __restrict__ ue, float* __restrict__ uclean, float* __restrict__ unstd)
{
    __shared__ __align__(16) float te[D_];
    __shared__ float pcl[N_];
    __shared__ float pnz[2][N_];
    const int s = blockIdx.x;
    const int tid = threadIdx.x;
    for (int d = tid; d < D_; d += 256) te[d] = ue[(size_t)s * D_ + d];
    __syncthreads();
    const int wave = tid >> 6;
    const int lane = tid & 63;

    // clean logits: wave handles n in [wave*32, wave*32+32)
    for (int j = 0; j < 32; ++j) {
        const int n = wave * 32 + j;
        const float* __restrict__ grow = gate_w + (size_t)n * (D_ + 1);
        float acc = 0.0f;
        #pragma unroll
        for (int k = 0; k < 16; ++k)
            acc += grow[k * 64 + lane] * te[k * 64 + lane];
        #pragma unroll
        for (int off = 32; off; off >>= 1) acc += __shfl_down(acc, off, 64);
        if (lane == 0) pcl[n] = acc;
    }

    // noise: wave w owns n = (w&1)*64 + lane over d-chunk [(w>>1)*512, +512)
    {
        const int n = (wave & 1) * 64 + lane;
        const int dbase = (wave >> 1) * 512;
        float acc = 0.0f;
        for (int d = 0; d < 512; ++d)
            acc += te[dbase + d] * w_noise[(size_t)(dbase + d) * N_ + n];
        pnz[wave >> 1][n] = acc;
    }
    __syncthreads();

    if (tid < N_) {
        const int step = timestep[0];
        float cl2 = pcl[tid]
                  + (float)step * gate_w[(size_t)tid * (D_ + 1) + D_]   // depth col
                  + gate_b[tid];
        uclean[s * N_ + tid] = cl2;
        float nz2 = pnz[0][tid] + pnz[1][tid];
        float sp = (nz2 > 20.0f) ? nz2 : log1pf(expf(nz2));   // softplus
        unstd[s * N_ + tid] = sp + NOISE_EPS_;
    }
}

// -------- Kernel 2: per-row gating + big masked-scale write -----------------
// grid B x 256 threads; block b writes out0[b, :, :] (128x1024 f32) + out1[b,:]
// Nontemporal stores keep prompts[step] resident in L2 (streaming writes do
// not allocate), so the 25% non-zero rows read from cache, not HBM.
__global__ __launch_bounds__(256) void out_kernel(
    const float* __restrict__ pe,     // [28,128,1024]
    const float* __restrict__ noise,  // [B,128]
    const int* __restrict__ timestep,
    const float* __restrict__ ue, const float* __restrict__ uclean,
    const float* __restrict__ unstd,
    float* __restrict__ out0, float* __restrict__ out1)
{
    __shared__ float noisy[N_];
    __shared__ float gates[N_];
    __shared__ float inv_sum;
    const int b = blockIdx.x;
    const int tid = threadIdx.x;
    const int tb = timestep[b];
    const int step = timestep[0];

    if (tid < N_) {
        noisy[tid] = uclean[tb * N_ + tid]
                   + noise[(size_t)b * N_ + tid] * unstd[tb * N_ + tid];
    }

    // out1: t_embed[b,:] = ue[tb,:]  (28 unique 4KB rows -> L2-resident reads)
    {
        const fx4* __restrict__ uer = (const fx4*)(ue + (size_t)tb * D_);
        fx4* __restrict__ o1 = (fx4*)(out1 + (size_t)b * D_);
        for (int i = tid; i < D_ / 4; i += 256)
            __builtin_nontemporal_store(uer[i], o1 + i);
    }
    __syncthreads();

    if (tid < N_) {
        const float v = noisy[tid];
        int rank = 0; float mx = -INFINITY;
        for (int m = 0; m < N_; ++m) {
            float u = noisy[m];
            mx = fmaxf(mx, u);
            rank += ((u > v) || (u == v && m < tid)) ? 1 : 0;   // lax.top_k tie-break
        }
        gates[tid] = (rank < KSEL) ? expf(v - mx) : 0.0f;
    }
    __syncthreads();
    if (tid < 64) {
        float s2 = gates[tid] + gates[tid + 64];
        #pragma unroll
        for (int off = 32; off; off >>= 1) s2 += __shfl_down(s2, off, 64);
        if (tid == 0) inv_sum = 1.0f / s2;
    }
    __syncthreads();
    if (tid < N_) gates[tid] *= inv_sum;
    __syncthreads();

    // big write: out0[b,n,d] = prompts[step,n,d] * gates[n]
    // idx = tid + it*256 -> n == it (uniform per iteration, no divergence)
    const fx4* __restrict__ psrc = (const fx4*)(pe + (size_t)step * N_ * D_);
    fx4* __restrict__ pdst = (fx4*)(out0 + (size_t)b * N_ * D_);
    for (int it = 0; it < N_; ++it) {
        const float g = gates[it];
        const int idx = it * 256 + tid;
        fx4 o;
        if (g != 0.0f) {
            fx4 u = psrc[idx];
            o = u * g;
        } else {
            o = (fx4)0.0f;
        }
        __builtin_nontemporal_store(o, pdst + idx);
    }
}

extern "C" void kernel_launch(void* const* d_in, const int* in_sizes, int n_in,
                              void* d_out, int out_size, void* d_ws, size_t ws_size,
                              hipStream_t stream) {
    (void)in_sizes; (void)n_in; (void)out_size; (void)ws_size;
    const float* pe      = (const float*)d_in[0];
    const float* w1      = (const float*)d_in[1];
    const float* b1      = (const float*)d_in[2];
    const float* w2      = (const float*)d_in[3];
    const float* b2      = (const float*)d_in[4];
    const float* gate_w  = (const float*)d_in[5];
    const float* gate_b  = (const float*)d_in[6];
    const float* w_noise = (const float*)d_in[7];
    const float* noise   = (const float*)d_in[8];
    const int*   ts      = (const int*)d_in[9];

    float* ws     = (float*)d_ws;
    float* ue     = ws;                         // 28*1024 fp32
    float* uclean = ue + PT_ * D_;              // 28*128
    float* unstd  = uclean + PT_ * N_;          // 28*128

    float* out0 = (float*)d_out;                       // [B,N,D]
    float* out1 = out0 + (size_t)B_ * N_ * D_;         // [B,D]

    hipLaunchKernelGGL(embed_kernel, dim3(PT_, 8), dim3(256), 0, stream,
                       w1, b1, w2, b2, ue);
    hipLaunchKernelGGL(gate_precompute_kernel, dim3(PT_), dim3(256), 0, stream,
                       gate_w, gate_b, w_noise, ts, ue, uclean, unstd);
    hipLaunchKernelGGL(out_kernel, dim3(B_), dim3(256), 0, stream,
                       pe, noise, ts, ue, uclean, unstd, out0, out1);
}